// Round 7
// baseline (252.575 us; speedup 1.0000x reference)
//
#include <hip/hip_runtime.h>

#define NETS 32
#define BATCH 4096
#define D0 256
#define D1 512
#define D2 512
#define D3 128
#define MT 128           // batch rows per block
#define LDA (D0 + 8)     // 264 halves -> 4-bank rotation per row
#define LDH (D1 + 8)     // 520 halves

using half8  = __attribute__((ext_vector_type(8))) _Float16;
using f32x16 = __attribute__((ext_vector_type(16))) float;

#define W1_N (NETS * D1 * D0)   // 4,194,304
#define W2_N (NETS * D2 * D1)   // 8,388,608
#define W3_N (NETS * D3 * D2)   // 2,097,152
#define X_N  (BATCH * D0)       // 1,048,576

// ---------------- prologue: fp32 -> fp16 cast + fragment swizzle ----------------
// Fragment layout (32x32x16 B-operand), identical to the R6-validated one:
// f = ((net*4 + wn)*NKK + kk)*NI + ni, 512 halves; lane l = oct*32+m owns
// W[net][wn*NI*32 + ni*32 + m][kk*16 + oct*8 + j], j=0..7.
// Thread ordering here is m-fastest so WRITES are coalesced (4x 512-B runs per
// wave); reads are 64 scattered full 64-B lines per wave.
template<int N, int K, int NI>
__device__ __forceinline__ void cvt_w(const float* __restrict__ W, _Float16* __restrict__ Wh, int u) {
    constexpr int NKK = K / 16;
    const int m  = u & 31;
    const int f  = u >> 5;
    const int ni = f % NI;
    const int rest = f / NI;
    const int kk = rest % NKK;
    const int g  = rest / NKK;
    const int wn = g & 3;
    const int net = g >> 2;
    const int n = wn * (NI * 32) + ni * 32 + m;
    const float* src = W + (size_t)net * N * K + (size_t)n * K + kk * 16;
    float4 v0 = *reinterpret_cast<const float4*>(src);
    float4 v1 = *reinterpret_cast<const float4*>(src + 4);
    float4 v2 = *reinterpret_cast<const float4*>(src + 8);
    float4 v3 = *reinterpret_cast<const float4*>(src + 12);
    half8 o0, o1;
    o0[0] = (_Float16)v0.x; o0[1] = (_Float16)v0.y; o0[2] = (_Float16)v0.z; o0[3] = (_Float16)v0.w;
    o0[4] = (_Float16)v1.x; o0[5] = (_Float16)v1.y; o0[6] = (_Float16)v1.z; o0[7] = (_Float16)v1.w;
    o1[0] = (_Float16)v2.x; o1[1] = (_Float16)v2.y; o1[2] = (_Float16)v2.z; o1[3] = (_Float16)v2.w;
    o1[4] = (_Float16)v3.x; o1[5] = (_Float16)v3.y; o1[6] = (_Float16)v3.z; o1[7] = (_Float16)v3.w;
    _Float16* dst = Wh + (size_t)f * 512 + m * 8;
    *reinterpret_cast<half8*>(dst)       = o0;   // lane m      (k-octet 0)
    *reinterpret_cast<half8*>(dst + 256) = o1;   // lane m + 32 (k-octet 1)
}

__global__ void cvt_all(const float* __restrict__ x,
                        const float* __restrict__ W1, const float* __restrict__ W2,
                        const float* __restrict__ W3,
                        _Float16* __restrict__ Xh,
                        _Float16* __restrict__ W1h, _Float16* __restrict__ W2h,
                        _Float16* __restrict__ W3h) {
    const int i = blockIdx.x * blockDim.x + threadIdx.x;
    constexpr int TX = X_N / 16, T1 = W1_N / 16, T2 = W2_N / 16;
    if (i < TX) {
        const float* src = x + (size_t)i * 16;
        float4 v0 = *reinterpret_cast<const float4*>(src);
        float4 v1 = *reinterpret_cast<const float4*>(src + 4);
        float4 v2 = *reinterpret_cast<const float4*>(src + 8);
        float4 v3 = *reinterpret_cast<const float4*>(src + 12);
        half8 o0, o1;
        o0[0] = (_Float16)v0.x; o0[1] = (_Float16)v0.y; o0[2] = (_Float16)v0.z; o0[3] = (_Float16)v0.w;
        o0[4] = (_Float16)v1.x; o0[5] = (_Float16)v1.y; o0[6] = (_Float16)v1.z; o0[7] = (_Float16)v1.w;
        o1[0] = (_Float16)v2.x; o1[1] = (_Float16)v2.y; o1[2] = (_Float16)v2.z; o1[3] = (_Float16)v2.w;
        o1[4] = (_Float16)v3.x; o1[5] = (_Float16)v3.y; o1[6] = (_Float16)v3.z; o1[7] = (_Float16)v3.w;
        _Float16* dst = Xh + (size_t)i * 16;
        *reinterpret_cast<half8*>(dst)     = o0;
        *reinterpret_cast<half8*>(dst + 8) = o1;
    }
    else if (i < TX + T1)           cvt_w<D1, D0, 4>(W1, W1h, i - TX);
    else if (i < TX + T1 + T2)      cvt_w<D2, D1, 4>(W2, W2h, i - TX - T1);
    else                            cvt_w<D3, D2, 1>(W3, W3h, i - TX - T1 - T2);
}

// ---------------- kk-granular pipelined layer, 32x32x16 MFMA ----------------
// B frags stream coalesced (1 KB/wave) from global, prefetched D kk-steps ahead
// in a rolling register buffer. A frags (MI 32-row tiles) from LDS.
template<int K, int NI, int MI, int D>
__device__ __forceinline__ void layer32(const _Float16* As, int lda,
                                        const _Float16* __restrict__ wl,
                                        int lane_m, int oct,
                                        f32x16 (&acc)[MI][NI]) {
    constexpr int NKK = K / 16;
    half8 b[D + 1][NI];
#pragma unroll
    for (int d = 0; d < D; ++d)
#pragma unroll
        for (int ni = 0; ni < NI; ++ni)
            b[d][ni] = *reinterpret_cast<const half8*>(wl + (size_t)(d * NI + ni) * 512);
#pragma unroll
    for (int kk = 0; kk < NKK; ++kk) {
        if (kk + D < NKK) {
            const int slot = (kk + D) % (D + 1);
#pragma unroll
            for (int ni = 0; ni < NI; ++ni)
                b[slot][ni] = *reinterpret_cast<const half8*>(
                    wl + (size_t)((kk + D) * NI + ni) * 512);
        }
        half8 a[MI];
#pragma unroll
        for (int mi = 0; mi < MI; ++mi)
            a[mi] = *reinterpret_cast<const half8*>(
                As + (mi * 32 + lane_m) * lda + kk * 16 + oct * 8);
        const int cs = kk % (D + 1);
#pragma unroll
        for (int ni = 0; ni < NI; ++ni)
#pragma unroll
            for (int mi = 0; mi < MI; ++mi)
                acc[mi][ni] = __builtin_amdgcn_mfma_f32_32x32x16_f16(a[mi], b[cs][ni], acc[mi][ni], 0, 0, 0);
    }
}

// C/D 32x32 layout: col = n_base + ni*32 + lane_m; row = mi*32 + (r&3) + 8*(r>>2) + 4*oct
template<int MI, int NI>
__device__ __forceinline__ void store_act32(f32x16 (&acc)[MI][NI], const float* __restrict__ bias,
                                            _Float16* dst, int ldd, int n_base,
                                            int lane_m, int oct) {
#pragma unroll
    for (int ni = 0; ni < NI; ++ni) {
        const int col = n_base + ni * 32 + lane_m;
        float bv = bias[col];
#pragma unroll
        for (int mi = 0; mi < MI; ++mi) {
#pragma unroll
            for (int r = 0; r < 16; ++r) {
                float v = acc[mi][ni][r] + bv;
                v = fmaxf(v, 0.0f);                        // relu
                int row = mi * 32 + (r & 3) + 8 * (r >> 2) + 4 * oct;
                dst[row * ldd + col] = (_Float16)v;
            }
        }
    }
}

// ---------------- fused 3-layer MLP: 512 threads, MT=128, 1 block/CU ----------------
// 8 waves = 2 m-groups (wm: 64 rows each) x 4 n-groups (wn: 128 cols each).
// Wave-pairs (wm=0/1, same wn) load identical B streams -> L1 dedup halves
// L2-side traffic; per-block M=128 halves unique B bytes per CU.
__global__ __launch_bounds__(512, 2) void mlp_fused(
    const _Float16* __restrict__ Xh,
    const _Float16* __restrict__ W1h, const float* __restrict__ b1,
    const _Float16* __restrict__ W2h, const float* __restrict__ b2,
    const _Float16* __restrict__ W3h, const float* __restrict__ b3,
    float* __restrict__ out) {
    __shared__ __align__(16) _Float16 buf[MT * LDH];   // X (LDA layout) -> H1 -> H2 (LDH); 133 KB

    const int tid = threadIdx.x;
    const int w = tid >> 6;
    const int wn = w & 3;          // n-group: 128 cols (NI=4)
    const int wm = w >> 2;         // m-group: 64 rows (MI=2)
    const int l = tid & 63;
    const int lane_m = l & 31;
    const int oct = l >> 5;

    // XCD-locality: round-robin dispatch -> 4 nets/XCD.
    const int bb = blockIdx.x;            // 0..1023
    const int xcd = bb & 7;
    const int s = bb >> 3;                // 0..127
    const int net = xcd * 4 + (s >> 5);   // 0..31
    const int mt = s & 31;                // 0..31
    const int m0 = mt * MT;

    // ---- stage X tile [MT][D0] fp16 into buf (LDA layout), 16-B copies ----
    {
        const _Float16* xsrc = Xh + (size_t)m0 * D0;
#pragma unroll
        for (int it = 0; it < 8; ++it) {
            int chunk = it * 512 + tid;   // 0..4095; 32 half8 per row
            int row = chunk >> 5;
            int c8 = chunk & 31;
            *reinterpret_cast<half8*>(&buf[row * LDA + c8 * 8]) =
                *reinterpret_cast<const half8*>(xsrc + row * D0 + c8 * 8);
        }
    }
    __syncthreads();

    // ---- layer 1: H1 = relu(X @ W1^T + b1), K=256, N=512 ----
    {
        f32x16 acc[2][4] = {};
        const _Float16* wl = W1h + ((size_t)(net * 4 + wn) * 64) * 512 + l * 8;
        layer32<D0, 4, 2, 2>(buf + wm * 64 * LDA, LDA, wl, lane_m, oct, acc);
        __syncthreads();                               // all X reads done
        store_act32<2, 4>(acc, b1 + net * D1, buf + wm * 64 * LDH, LDH, wn * 128, lane_m, oct);
    }
    __syncthreads();

    // ---- layer 2: H2 = relu(H1 @ W2^T + b2), K=512, N=512 ----
    {
        f32x16 acc[2][4] = {};
        const _Float16* wl = W2h + ((size_t)(net * 4 + wn) * 128) * 512 + l * 8;
        layer32<D1, 4, 2, 2>(buf + wm * 64 * LDH, LDH, wl, lane_m, oct, acc);
        __syncthreads();                               // all H1 reads done
        store_act32<2, 4>(acc, b2 + net * D2, buf + wm * 64 * LDH, LDH, wn * 128, lane_m, oct);
    }
    __syncthreads();

    // ---- layer 3: out = H2 @ W3^T + b3, K=512, N=128 (wn owns 32 cols) ----
    {
        f32x16 acc[2][1] = {};
        const _Float16* wl = W3h + ((size_t)(net * 4 + wn) * 32) * 512 + l * 8;
        layer32<D2, 1, 2, 8>(buf + wm * 64 * LDH, LDH, wl, lane_m, oct, acc);
        const int col = net * D3 + wn * 32 + lane_m;
        float bv = b3[net * D3 + wn * 32 + lane_m];
#pragma unroll
        for (int mi = 0; mi < 2; ++mi) {
#pragma unroll
            for (int r = 0; r < 16; ++r) {
                int row = m0 + wm * 64 + mi * 32 + (r & 3) + 8 * (r >> 2) + 4 * oct;
                out[(size_t)row * (NETS * D3) + col] = acc[mi][0][r] + bv;
            }
        }
    }
}

extern "C" void kernel_launch(void* const* d_in, const int* in_sizes, int n_in,
                              void* d_out, int out_size, void* d_ws, size_t ws_size,
                              hipStream_t stream) {
    const float* x  = (const float*)d_in[0];
    const float* W1 = (const float*)d_in[1];
    const float* b1 = (const float*)d_in[2];
    const float* W2 = (const float*)d_in[3];
    const float* b2 = (const float*)d_in[4];
    const float* W3 = (const float*)d_in[5];
    const float* b3 = (const float*)d_in[6];
    float* out = (float*)d_out;

    // ws layout (fp16): Xh | W1h | W2h | W3h  = ~31.5 MB total
    _Float16* Xh  = (_Float16*)d_ws;
    _Float16* W1h = Xh  + (size_t)X_N;
    _Float16* W2h = W1h + (size_t)W1_N;
    _Float16* W3h = W2h + (size_t)W2_N;

    const int totalT = (X_N + W1_N + W2_N + W3_N) / 16;    // 983,040 threads
    cvt_all<<<totalT / 256, 256, 0, stream>>>(x, W1, W2, W3, Xh, W1h, W2h, W3h);

    mlp_fused<<<NETS * (BATCH / MT), 512, 0, stream>>>(Xh, W1h, b1, W2h, b2, W3h, b3, out);
}